// Round 12
// baseline (165.370 us; speedup 1.0000x reference)
//
#include <hip/hip_runtime.h>
#include <hip/hip_fp16.h>
#include <hip/hip_cooperative_groups.h>

namespace cg = cooperative_groups;

#define NSTEPS 10
#define D_IN   14400
#define KNN_K  25

#define L0D 7200
#define L1D 3600
#define L2D 1800
#define L3D 900
#define L4D 450

#define NBLK 256
#define NTHR 512
#define NWAVE (NBLK * (NTHR / 64))   // 2048 waves grid-wide

__device__ __forceinline__ unsigned f16b(float x) {
    return (unsigned)__half_as_ushort(__float2half_rn(x));
}

// ---- tail helper: per-thread row gather from LDS (2 batches per u32 word) ----
__device__ __forceinline__ void tail_layer(const unsigned* __restrict__ src,
                                           unsigned* __restrict__ dst,
                                           const int* __restrict__ kp,
                                           const float* __restrict__ wp,
                                           const float* __restrict__ bp,
                                           int dim, int tid)
{
    for (int r = tid; r < dim; r += NTHR) {
        const int*   kr = kp + r * KNN_K;
        const float* wr = wp + r * KNN_K;
        float a0 = bp[r], a1 = a0;
#pragma unroll 5
        for (int k = 0; k < KNN_K; ++k) {
            const unsigned av = src[kr[k]];
            const float    wf = wr[k];
            const __half2  h  = *(const __half2*)&av;
            a0 = fmaf(__half2float(__low2half(h)),  wf, a0);   // v_fma_mix_f32
            a1 = fmaf(__half2float(__high2half(h)), wf, a1);
        }
        dst[r] = f16b(a0) | (f16b(a1) << 16);
    }
}

// ---- single cooperative kernel: transpose | L0 | L1 | tail, grid.sync between ----
__global__ __launch_bounds__(NTHR, 2)
void lcn_coop(const float* __restrict__ input,
              const int* __restrict__ k0, const float* __restrict__ w0, const float* __restrict__ b0,
              const int* __restrict__ k1, const float* __restrict__ w1, const float* __restrict__ b1,
              const int* __restrict__ k2, const float* __restrict__ w2, const float* __restrict__ b2,
              const int* __restrict__ k3, const float* __restrict__ w3, const float* __restrict__ b3,
              const int* __restrict__ k4, const float* __restrict__ w4, const float* __restrict__ b4,
              const float* __restrict__ fcw, const float* __restrict__ fcb,
              __half* __restrict__ X0, __half* __restrict__ Y0,
              unsigned* __restrict__ Y1p, float* __restrict__ out)
{
    cg::grid_group grid = cg::this_grid();
    __shared__ __align__(16) char smraw[27008];    // union: transpose tile / tail regions
    const int tid = threadIdx.x;

    // ---- phase 0: transpose input[:, 9, :] -> X0[feature][batch] f16 (batch-major) ----
    {
        float (*tile)[65] = (float (*)[65])smraw;  // 64x65 f32, conflict-free both ways
        const int tx = tid & 63, ty = tid >> 6;    // ty: 0..7
        for (int t = blockIdx.x; t < 900; t += NBLK) {
            const int d0 = (t % 225) * 64;
            const int bb = (t / 225) * 64;
            __syncthreads();                        // protect LDS reuse across tiles
#pragma unroll
            for (int i = 0; i < 8; ++i) {
                const int bl = ty * 8 + i;
                tile[bl][tx] = input[(size_t)(bb + bl) * (NSTEPS * D_IN)
                                     + (size_t)(NSTEPS - 1) * D_IN + d0 + tx];
            }
            __syncthreads();
#pragma unroll
            for (int i = 0; i < 8; ++i) {
                const int dl = ty * 8 + i;
                X0[(size_t)(d0 + dl) * 256 + bb + tx] = __float2half_rn(tile[tx][dl]);
            }
        }
    }
    grid.sync();

    const int lane = tid & 63;
    const int wid  = __builtin_amdgcn_readfirstlane(blockIdx.x * (NTHR / 64) + (tid >> 6));

    // ---- phase 1: L0 (7200 rows). one wave per row; lane owns 4 batches;
    //      each of 25 gathers is a fully-coalesced 512B row read from L2;
    //      knn/w/bias rows are wave-uniform -> s_load; weights stay f32 ----
    for (int r = wid; r < L0D; r += NWAVE) {
        const int*   kr = k0 + r * KNN_K;
        const float* wr = w0 + r * KNN_K;
        float a0 = b0[r], a1 = a0, a2 = a0, a3 = a0;
#pragma unroll 5
        for (int k = 0; k < KNN_K; ++k) {
            const int   idx = kr[k];
            const float wf  = wr[k];
            const uint2 xv  = *(const uint2*)(X0 + (size_t)idx * 256 + lane * 4);
            const __half2 x01 = *(const __half2*)&xv.x;
            const __half2 x23 = *(const __half2*)&xv.y;
            a0 = fmaf(__half2float(__low2half(x01)),  wf, a0);
            a1 = fmaf(__half2float(__high2half(x01)), wf, a1);
            a2 = fmaf(__half2float(__low2half(x23)),  wf, a2);
            a3 = fmaf(__half2float(__high2half(x23)), wf, a3);
        }
        uint2 o;
        o.x = f16b(a0) | (f16b(a1) << 16);
        o.y = f16b(a2) | (f16b(a3) << 16);
        *(uint2*)(Y0 + (size_t)r * 256 + lane * 4) = o;
    }
    grid.sync();

    // ---- phase 2: L1 (3600 rows), same gather on Y0; writes PAIR-MAJOR Y1p[pair][3600] ----
    for (int r = wid; r < L1D; r += NWAVE) {
        const int*   kr = k1 + r * KNN_K;
        const float* wr = w1 + r * KNN_K;
        float a0 = b1[r], a1 = a0, a2 = a0, a3 = a0;
#pragma unroll 5
        for (int k = 0; k < KNN_K; ++k) {
            const int   idx = kr[k];
            const float wf  = wr[k];
            const uint2 xv  = *(const uint2*)(Y0 + (size_t)idx * 256 + lane * 4);
            const __half2 x01 = *(const __half2*)&xv.x;
            const __half2 x23 = *(const __half2*)&xv.y;
            a0 = fmaf(__half2float(__low2half(x01)),  wf, a0);
            a1 = fmaf(__half2float(__high2half(x01)), wf, a1);
            a2 = fmaf(__half2float(__low2half(x23)),  wf, a2);
            a3 = fmaf(__half2float(__high2half(x23)), wf, a3);
        }
        // lane owns batches 4l..4l+3 = pairs 2l (a0,a1) and 2l+1 (a2,a3)
        Y1p[(size_t)(2 * lane)     * L1D + r] = f16b(a0) | (f16b(a1) << 16);
        Y1p[(size_t)(2 * lane + 1) * L1D + r] = f16b(a2) | (f16b(a3) << 16);
    }
    grid.sync();

    // ---- phase 3: tail on blocks 0..127 (one batch-pair each): L2,L3,L4 in LDS + FC ----
    if (blockIdx.x >= 128) return;
    unsigned* R1 = (unsigned*)smraw;   // 3600
    unsigned* R2 = R1 + L1D;           // 1800
    unsigned* R3 = R2 + L2D;           // 900
    unsigned* R4 = R3 + L3D;           // 450   (total 6750 u32 = 27000 B)
    const int p = blockIdx.x;

    __syncthreads();                   // LDS reuse after phase 0
    for (int d = tid; d < L1D; d += NTHR)
        R1[d] = Y1p[(size_t)p * L1D + d];
    __syncthreads();

    tail_layer(R1, R2, k2, w2, b2, L2D, tid);
    __syncthreads();
    tail_layer(R2, R3, k3, w3, b3, L3D, tid);
    __syncthreads();
    tail_layer(R3, R4, k4, w4, b4, L4D, tid);
    __syncthreads();

    // FC: 4 waves -> (out channel o, batch-in-pair j)
    if (tid < 256) {
        const int wv = tid >> 6, l = tid & 63;
        const int o = wv >> 1, j = wv & 1;
        float s = 0.f;
#pragma unroll
        for (int it = 0; it < 8; ++it) {
            const int r = l + it * 64;
            if (r < L4D) {
                const __half2 h = *(const __half2*)&R4[r];
                s += __half2float(j ? __high2half(h) : __low2half(h)) * fcw[o * L4D + r];
            }
        }
#pragma unroll
        for (int off = 32; off > 0; off >>= 1) s += __shfl_xor(s, off);
        if (l == 0) out[(2 * p + j) * 2 + o] = s + fcb[o];
    }
}

extern "C" void kernel_launch(void* const* d_in, const int* in_sizes, int n_in,
                              void* d_out, int out_size, void* d_ws, size_t ws_size,
                              hipStream_t stream) {
    const float* input = (const float*)d_in[0];
    const int*   knn[5];
    const float* w[5];
    const float* bias[5];
    for (int i = 0; i < 5; ++i) {
        knn[i]  = (const int*)  d_in[1 + 3 * i];
        w[i]    = (const float*)d_in[2 + 3 * i];
        bias[i] = (const float*)d_in[3 + 3 * i];
    }
    const float* fc_w = (const float*)d_in[16];
    const float* fc_b = (const float*)d_in[17];
    float* outp = (float*)d_out;

    // ws layout (16B-aligned): X0 (7.373 MB) | Y0 (3.686 MB) | Y1p (1.843 MB)
    char* base = (char*)d_ws;
    __half*   X0  = (__half*)base;
    __half*   Y0  = (__half*)(base + (size_t)D_IN * 256 * 2);
    unsigned* Y1p = (unsigned*)(base + (size_t)(D_IN + L0D) * 256 * 2);

    void* args[] = {
        (void*)&input,
        (void*)&knn[0], (void*)&w[0], (void*)&bias[0],
        (void*)&knn[1], (void*)&w[1], (void*)&bias[1],
        (void*)&knn[2], (void*)&w[2], (void*)&bias[2],
        (void*)&knn[3], (void*)&w[3], (void*)&bias[3],
        (void*)&knn[4], (void*)&w[4], (void*)&bias[4],
        (void*)&fc_w, (void*)&fc_b,
        (void*)&X0, (void*)&Y0, (void*)&Y1p, (void*)&outp
    };
    hipLaunchCooperativeKernel((const void*)lcn_coop, dim3(NBLK), dim3(NTHR),
                               args, 0, stream);
}